// Round 5
// baseline (4258.476 us; speedup 1.0000x reference)
//
#include <hip/hip_runtime.h>
#include <stdint.h>

#define B_ 256
#define S_ 512
#define H_ 512

// Dynamic LDS layout (bytes):
//   [0,16384)        imp_lds : W_imp B-tile, REPLICATED across all 16 cols
//                              (=> every lane's acc4[r] is a valid imp for its row)
//   [16384,82048)    xm_lds  : packed (x*(1-m), m) bf16 pairs, [32 rows][513 dwords] (+1 pad
//                              breaks the 512-dword same-bank stride)
// total 82,048 -> request 82,176 (>80 KiB => exactly 1 wg/CU).
#define XM_STRIDE 513
#define LDS_BYTES 82176

typedef __attribute__((ext_vector_type(4))) float f32x4;
typedef __attribute__((ext_vector_type(4))) int   i32x4;
typedef __attribute__((ext_vector_type(8))) short s16x8;

__device__ __forceinline__ short f2bf(float f) {
    union { float f; uint32_t u; } c; c.f = f;
    uint32_t u = c.u;
    u += 0x7fffu + ((u >> 16) & 1u);   // round-to-nearest-even
    return (short)(u >> 16);
}
__device__ __forceinline__ float bflo(uint32_t u) { return __builtin_bit_cast(float, u << 16); }
__device__ __forceinline__ float bfhi(uint32_t u) { return __builtin_bit_cast(float, u & 0xffff0000u); }
__device__ __forceinline__ float sig_(float x)  { return 1.0f / (1.0f + __expf(-x)); }
__device__ __forceinline__ float tanh_(float x) { return 1.0f - 2.0f / (1.0f + __expf(2.0f * x)); }

// Issue 16 A-fragment loads, NO wait (progressive vmcnt waits follow).
// sc0 sc1 = read at the LLC (cross-XCD coherence point) — placement-independent correctness.
__device__ __forceinline__ void load_a16_issue(const void* p, i32x4* a) {
    asm volatile(
        "global_load_dwordx4 %0, %16, off sc0 sc1\n\t"
        "global_load_dwordx4 %1, %16, off offset:64 sc0 sc1\n\t"
        "global_load_dwordx4 %2, %16, off offset:128 sc0 sc1\n\t"
        "global_load_dwordx4 %3, %16, off offset:192 sc0 sc1\n\t"
        "global_load_dwordx4 %4, %16, off offset:256 sc0 sc1\n\t"
        "global_load_dwordx4 %5, %16, off offset:320 sc0 sc1\n\t"
        "global_load_dwordx4 %6, %16, off offset:384 sc0 sc1\n\t"
        "global_load_dwordx4 %7, %16, off offset:448 sc0 sc1\n\t"
        "global_load_dwordx4 %8, %16, off offset:512 sc0 sc1\n\t"
        "global_load_dwordx4 %9, %16, off offset:576 sc0 sc1\n\t"
        "global_load_dwordx4 %10, %16, off offset:640 sc0 sc1\n\t"
        "global_load_dwordx4 %11, %16, off offset:704 sc0 sc1\n\t"
        "global_load_dwordx4 %12, %16, off offset:768 sc0 sc1\n\t"
        "global_load_dwordx4 %13, %16, off offset:832 sc0 sc1\n\t"
        "global_load_dwordx4 %14, %16, off offset:896 sc0 sc1\n\t"
        "global_load_dwordx4 %15, %16, off offset:960 sc0 sc1"
        : "=v"(a[0]), "=v"(a[1]), "=v"(a[2]), "=v"(a[3]),
          "=v"(a[4]), "=v"(a[5]), "=v"(a[6]), "=v"(a[7]),
          "=v"(a[8]), "=v"(a[9]), "=v"(a[10]), "=v"(a[11]),
          "=v"(a[12]), "=v"(a[13]), "=v"(a[14]), "=v"(a[15])
        : "v"(p)
        : "memory");
}
// Progressive wait; ties the consumed fragments through the asm so MFMAs can't be hoisted above it.
#define AWAIT(imm, x0, x1, x2, x3) \
    asm volatile("s_waitcnt vmcnt(" #imm ")" : "+v"(x0), "+v"(x1), "+v"(x2), "+v"(x3) :: "memory")

// Write-through-to-LLC h stores (visible device-wide once vmcnt drains).
__device__ __forceinline__ void store_h4(void* p, int h0, int h1, int h2, int h3) {
    asm volatile(
        "global_store_short %4, %0, off sc0 sc1\n\t"
        "global_store_short %4, %1, off offset:1024 sc0 sc1\n\t"
        "global_store_short %4, %2, off offset:2048 sc0 sc1\n\t"
        "global_store_short %4, %3, off offset:3072 sc0 sc1"
        :: "v"(h0), "v"(h1), "v"(h2), "v"(h3), "v"(p)
        : "memory");
}

__global__ void __launch_bounds__(256, 1)
lstm_kernel(const float* __restrict__ values, const float* __restrict__ masks,
            const float* __restrict__ Wih_f, const float* __restrict__ Whh_f,
            const float* __restrict__ bih_f, const float* __restrict__ bhh_f,
            const float* __restrict__ Wih_b, const float* __restrict__ Whh_b,
            const float* __restrict__ bih_b, const float* __restrict__ bhh_b,
            const float* __restrict__ W_imp, const float* __restrict__ b_imp,
            unsigned int* ctrs, short* h_buf, float* hfin)
{
    extern __shared__ char smem_raw[];
    short*    imp_lds = (short*)smem_raw;
    uint32_t* xm_lds  = (uint32_t*)(smem_raw + 16384);

    // flags[16 clusters][2 mw][16 w][2 nw] dwords = 4 KB, at ws +256 B
    uint32_t* flags = (uint32_t*)ctrs + 64;

    const int tid  = threadIdx.x;
    const int lane = tid & 63;
    const int wave = tid >> 6;
    const int mw = wave >> 1;      // M-wave: batch half (rows mw*16 .. +15)
    const int nw = wave & 1;       // N-wave: hcol half

    // Static cluster decomposition (bounded, deadlock-impossible).
    const int bid = blockIdx.x;
    const int xg  = bid & 7;       // batch group 0..7
    const int s_  = bid >> 3;
    const int d   = s_ & 1;        // direction
    const int w   = s_ >> 1;       // wg-in-cluster 0..15 (owns hcols w*32..w*32+31)
    const int cluster = xg * 2 + d;

    const float* Whh = d ? Whh_b : Whh_f;
    const float* Wih = d ? Wih_b : Wih_f;
    const float* bih = d ? bih_b : bih_f;
    const float* bhh = d ? bhh_b : bhh_f;

    const int col16 = lane & 15;
    const int koff4 = lane >> 4;                 // 0..3
    const int jcol  = w * 32 + nw * 16 + col16;  // owned h-column

    // ---- stage W_imp B-tile into LDS, replicated across all 16 cols ----
    // chunk c = (kb*4 + koff)*16 + col ; lane fragment = 8 bf16 at k = kb*32+koff*8
    for (int c = tid; c < 1024; c += 256) {
        int ckoff = (c >> 4) & 3, ckb = c >> 6;
        int k0 = ckb * 32 + ckoff * 8;
        short* dst = &imp_lds[c * 8];
        #pragma unroll
        for (int j = 0; j < 8; ++j) dst[j] = f2bf(W_imp[k0 + j]);
    }
    // ---- stage packed (x*(1-m), m) bf16 pairs for this wg's 32 batch rows ----
    for (int i = tid; i < 32 * 512; i += 256) {
        int r = i >> 9, s = i & 511;
        float x = values[(xg * 32 + r) * S_ + s];
        float m = masks[(xg * 32 + r) * S_ + s];
        float a = x * (1.0f - m);
        xm_lds[r * XM_STRIDE + s] =
            (uint32_t)(uint16_t)f2bf(a) | ((uint32_t)(uint16_t)f2bf(m) << 16);
    }

    // ---- B fragments (4 gate tiles) in registers: 256 VGPRs, static over all steps ----
    s16x8 bfr[4][16];
    {
        const float* base = Whh + (size_t)jcol * 512 + koff4 * 8;
        #pragma unroll
        for (int g = 0; g < 4; ++g) {
            const float* src = base + (size_t)g * 512 * 512;
            #pragma unroll
            for (int kb = 0; kb < 16; ++kb) {
                f32x4 v0 = *(const f32x4*)(src + kb * 32);
                f32x4 v1 = *(const f32x4*)(src + kb * 32 + 4);
                s16x8 b;
                b[0] = f2bf(v0[0]); b[1] = f2bf(v0[1]); b[2] = f2bf(v0[2]); b[3] = f2bf(v0[3]);
                b[4] = f2bf(v1[0]); b[5] = f2bf(v1[1]); b[6] = f2bf(v1[2]); b[7] = f2bf(v1[3]);
                bfr[g][kb] = b;
            }
        }
    }

    float bias[4], wih[4];
    #pragma unroll
    for (int g = 0; g < 4; ++g) {
        int gc = g * 512 + jcol;
        bias[g] = bih[gc] + bhh[gc];
        wih[g]  = Wih[gc];
    }
    const float bimp  = b_imp[0];
    const float start = d ? -128.0f : 128.0f;

    const int arow    = xg * 32 + mw * 16 + col16;      // A-fragment row (abs batch)
    const int rowloc  = mw * 16 + koff4 * 4;            // first local C-row of this lane
    const int rowbase = xg * 32 + rowloc;               // abs
    const int imp_off = (koff4 * 16 + col16) * 8;       // lds chunk offset within a kb block

    // per-WAVE flags: producer posts its own; consumer wave (mw) needs the 32
    // producer waves with the same mw => 32 contiguous dwords (2 cache lines).
    uint32_t*       myflag = flags + cluster * 64 + mw * 32 + w * 2 + nw;
    const uint32_t* pollp  = flags + cluster * 64 + mw * 32 + (lane & 31);

    __syncthreads();   // LDS staging complete (only barrier outside the prologue)

    // ---- init cell: h0,c0 = lstm_cell(start, 0, 0); post flag=1 per wave ----
    float c_reg[4];
    {
        float pre[4];
        #pragma unroll
        for (int g = 0; g < 4; ++g) pre[g] = start * wih[g] + bias[g];
        float i0 = sig_(pre[0]), g0 = tanh_(pre[2]), o0 = sig_(pre[3]);
        float c0 = i0 * g0;
        float h0 = o0 * tanh_(c0);
        #pragma unroll
        for (int r = 0; r < 4; ++r) c_reg[r] = c0;
        int hb16 = (int)(unsigned short)(unsigned)f2bf(h0);
        short* dst = h_buf + d * (B_ * H_) + (size_t)rowbase * H_ + jcol;  // buffer 0 holds h_0
        store_h4(dst, hb16, hb16, hb16, hb16);
    }
    asm volatile("s_waitcnt vmcnt(0)" ::: "memory");
    if (lane == 0)
        asm volatile("global_store_dword %0, %1, off sc0 sc1" :: "v"(myflag), "v"(1u) : "memory");

    // ---- sequential scan: fully wave-autonomous (no intra-wg barriers) ----
    for (int t = 0; t < S_; ++t) {
        const int p = t & 1;
        const short* hb_r = h_buf + p       * (2 * B_ * H_) + d * (B_ * H_);
        short*       hb_w = h_buf + (p ^ 1) * (2 * B_ * H_) + d * (B_ * H_);

        // poll the 32 producer-wave flags (2 LLC lines); backoff only on failure
        {
            const uint32_t tgt = (uint32_t)(t + 1);
            for (;;) {
                uint32_t f;
                asm volatile("global_load_dword %0, %1, off sc0 sc1\n\ts_waitcnt vmcnt(0)"
                             : "=v"(f) : "v"(pollp) : "memory");
                if (__ballot(f >= tgt) == ~0ull) break;
                __builtin_amdgcn_s_sleep(1);
            }
        }

        // A fragments from LLC; waits pipelined under MFMA
        i32x4 a_regs[16];
        load_a16_issue(hb_r + (size_t)arow * H_ + koff4 * 8, a_regs);

        f32x4 acc0 = {0,0,0,0}, acc1 = {0,0,0,0}, acc2 = {0,0,0,0}, acc3 = {0,0,0,0};
        f32x4 acc4 = {0,0,0,0};   // imp (W_imp replicated => valid in every lane)
        AWAIT(12, a_regs[0], a_regs[1], a_regs[2], a_regs[3]);
        #pragma unroll
        for (int kb = 0; kb < 4; ++kb) {
            s16x8 a = __builtin_bit_cast(s16x8, a_regs[kb]);
            acc0 = __builtin_amdgcn_mfma_f32_16x16x32_bf16(a, bfr[0][kb], acc0, 0, 0, 0);
            acc1 = __builtin_amdgcn_mfma_f32_16x16x32_bf16(a, bfr[1][kb], acc1, 0, 0, 0);
            acc2 = __builtin_amdgcn_mfma_f32_16x16x32_bf16(a, bfr[2][kb], acc2, 0, 0, 0);
            acc3 = __builtin_amdgcn_mfma_f32_16x16x32_bf16(a, bfr[3][kb], acc3, 0, 0, 0);
            s16x8 b4 = *(const s16x8*)&imp_lds[kb * 512 + imp_off];
            acc4 = __builtin_amdgcn_mfma_f32_16x16x32_bf16(a, b4, acc4, 0, 0, 0);
        }
        AWAIT(8, a_regs[4], a_regs[5], a_regs[6], a_regs[7]);
        #pragma unroll
        for (int kb = 4; kb < 8; ++kb) {
            s16x8 a = __builtin_bit_cast(s16x8, a_regs[kb]);
            acc0 = __builtin_amdgcn_mfma_f32_16x16x32_bf16(a, bfr[0][kb], acc0, 0, 0, 0);
            acc1 = __builtin_amdgcn_mfma_f32_16x16x32_bf16(a, bfr[1][kb], acc1, 0, 0, 0);
            acc2 = __builtin_amdgcn_mfma_f32_16x16x32_bf16(a, bfr[2][kb], acc2, 0, 0, 0);
            acc3 = __builtin_amdgcn_mfma_f32_16x16x32_bf16(a, bfr[3][kb], acc3, 0, 0, 0);
            s16x8 b4 = *(const s16x8*)&imp_lds[kb * 512 + imp_off];
            acc4 = __builtin_amdgcn_mfma_f32_16x16x32_bf16(a, b4, acc4, 0, 0, 0);
        }
        AWAIT(4, a_regs[8], a_regs[9], a_regs[10], a_regs[11]);
        #pragma unroll
        for (int kb = 8; kb < 12; ++kb) {
            s16x8 a = __builtin_bit_cast(s16x8, a_regs[kb]);
            acc0 = __builtin_amdgcn_mfma_f32_16x16x32_bf16(a, bfr[0][kb], acc0, 0, 0, 0);
            acc1 = __builtin_amdgcn_mfma_f32_16x16x32_bf16(a, bfr[1][kb], acc1, 0, 0, 0);
            acc2 = __builtin_amdgcn_mfma_f32_16x16x32_bf16(a, bfr[2][kb], acc2, 0, 0, 0);
            acc3 = __builtin_amdgcn_mfma_f32_16x16x32_bf16(a, bfr[3][kb], acc3, 0, 0, 0);
            s16x8 b4 = *(const s16x8*)&imp_lds[kb * 512 + imp_off];
            acc4 = __builtin_amdgcn_mfma_f32_16x16x32_bf16(a, b4, acc4, 0, 0, 0);
        }
        AWAIT(0, a_regs[12], a_regs[13], a_regs[14], a_regs[15]);
        #pragma unroll
        for (int kb = 12; kb < 16; ++kb) {
            s16x8 a = __builtin_bit_cast(s16x8, a_regs[kb]);
            acc0 = __builtin_amdgcn_mfma_f32_16x16x32_bf16(a, bfr[0][kb], acc0, 0, 0, 0);
            acc1 = __builtin_amdgcn_mfma_f32_16x16x32_bf16(a, bfr[1][kb], acc1, 0, 0, 0);
            acc2 = __builtin_amdgcn_mfma_f32_16x16x32_bf16(a, bfr[2][kb], acc2, 0, 0, 0);
            acc3 = __builtin_amdgcn_mfma_f32_16x16x32_bf16(a, bfr[3][kb], acc3, 0, 0, 0);
            s16x8 b4 = *(const s16x8*)&imp_lds[kb * 512 + imp_off];
            acc4 = __builtin_amdgcn_mfma_f32_16x16x32_bf16(a, b4, acc4, 0, 0, 0);
        }

        // per-lane cc + gates -> c,h ; no cross-lane traffic at all
        int hbits[4];
        #pragma unroll
        for (int r = 0; r < 4; ++r) {
            uint32_t pk = xm_lds[(rowloc + r) * XM_STRIDE + t];
            float cc = bflo(pk) + bfhi(pk) * (acc4[r] + bimp);
            float pi = acc0[r] + cc * wih[0] + bias[0];
            float pf = acc1[r] + cc * wih[1] + bias[1];
            float pg = acc2[r] + cc * wih[2] + bias[2];
            float po = acc3[r] + cc * wih[3] + bias[3];
            float iv = sig_(pi), fv = sig_(pf), gv = tanh_(pg), ov = sig_(po);
            c_reg[r] = fv * c_reg[r] + iv * gv;
            float hn = ov * tanh_(c_reg[r]);
            hbits[r] = (int)(unsigned short)(unsigned)f2bf(hn);
            if (t == S_ - 1) hfin[d * (B_ * H_) + (rowbase + r) * H_ + jcol] = hn;
        }
        store_h4(hb_w + (size_t)rowbase * H_ + jcol, hbits[0], hbits[1], hbits[2], hbits[3]);

        // drain own stores to LLC, then post this wave's flag (plain store, no RMW, no barrier)
        asm volatile("s_waitcnt vmcnt(0)" ::: "memory");
        if (lane == 0)
            asm volatile("global_store_dword %0, %1, off sc0 sc1"
                         :: "v"(myflag), "v"((uint32_t)(t + 2)) : "memory");
    }
}

__global__ void __launch_bounds__(256)
epilogue_kernel(const float* __restrict__ values, const float* __restrict__ masks,
                const float* __restrict__ hfin, float* __restrict__ out)
{
    int i = blockIdx.x * 256 + threadIdx.x;          // 0..131071
    float h = hfin[i] + hfin[B_ * H_ + i];           // h_f + h_b
    out[i] = h;                                      // output 0: h (B,H)
    float xv = values[i], mv = masks[i];
    out[B_ * H_ + i] = h * (1.0f - mv) + xv * mv;    // output 1: out (B,S,1)
}

extern "C" void kernel_launch(void* const* d_in, const int* in_sizes, int n_in,
                              void* d_out, int out_size, void* d_ws, size_t ws_size,
                              hipStream_t stream) {
    const float* values = (const float*)d_in[0];
    const float* masks  = (const float*)d_in[1];
    const float* Wih_f  = (const float*)d_in[2];
    const float* Whh_f  = (const float*)d_in[3];
    const float* bih_f  = (const float*)d_in[4];
    const float* bhh_f  = (const float*)d_in[5];
    const float* Wih_b  = (const float*)d_in[6];
    const float* Whh_b  = (const float*)d_in[7];
    const float* bih_b  = (const float*)d_in[8];
    const float* bhh_b  = (const float*)d_in[9];
    const float* W_imp  = (const float*)d_in[10];
    const float* b_imp  = (const float*)d_in[11];

    unsigned int* ctrs = (unsigned int*)d_ws;        // flags[16][2][16][2] @ +256 B
    short* h_buf = (short*)((char*)d_ws + 8192);     // 2 bufs x 2 dirs x 256x512 bf16 = 1 MB
    float* hfin  = (float*)((char*)d_ws + 8192 + 2 * 2 * B_ * H_ * sizeof(short));

    hipMemsetAsync(d_ws, 0, 8192, stream);           // zero flags

    hipFuncSetAttribute((const void*)lstm_kernel,
                        hipFuncAttributeMaxDynamicSharedMemorySize, LDS_BYTES);

    void* args[] = {
        (void*)&values, (void*)&masks,
        (void*)&Wih_f, (void*)&Whh_f, (void*)&bih_f, (void*)&bhh_f,
        (void*)&Wih_b, (void*)&Whh_b, (void*)&bih_b, (void*)&bhh_b,
        (void*)&W_imp, (void*)&b_imp,
        (void*)&ctrs, (void*)&h_buf, (void*)&hfin
    };
    hipError_t err = hipLaunchCooperativeKernel((const void*)lstm_kernel,
                                                dim3(256), dim3(256), args,
                                                (unsigned int)LDS_BYTES, stream);
    if (err != hipSuccess) {
        lstm_kernel<<<dim3(256), dim3(256), LDS_BYTES, stream>>>(
            values, masks, Wih_f, Whh_f, bih_f, bhh_f,
            Wih_b, Whh_b, bih_b, bhh_b, W_imp, b_imp, ctrs, h_buf, hfin);
    }

    epilogue_kernel<<<dim3((B_ * H_) / 256), dim3(256), 0, stream>>>(
        values, masks, hfin, (float*)d_out);
}

// Round 6
// 2736.307 us; speedup vs baseline: 1.5563x; 1.5563x over previous
//
#include <hip/hip_runtime.h>
#include <stdint.h>

#define B_ 256
#define S_ 512
#define H_ 512

// Dynamic LDS layout (bytes):
//   [0,16384)        imp_lds : W_imp B-tile, REPLICATED across all 16 cols
//   [16384,82048)    xm_lds  : packed (x*(1-m), m) bf16 pairs, [32 rows][513 dwords]
// total 82,048 -> request 82,176 (>80 KiB => exactly 1 wg/CU).
#define XM_STRIDE 513
#define LDS_BYTES 82176

typedef __attribute__((ext_vector_type(4))) float f32x4;
typedef __attribute__((ext_vector_type(4))) int   i32x4;
typedef __attribute__((ext_vector_type(8))) short s16x8;

__device__ __forceinline__ short f2bf(float f) {
    union { float f; uint32_t u; } c; c.f = f;
    uint32_t u = c.u;
    u += 0x7fffu + ((u >> 16) & 1u);   // round-to-nearest-even
    return (short)(u >> 16);
}
__device__ __forceinline__ float bflo(uint32_t u) { return __builtin_bit_cast(float, u << 16); }
__device__ __forceinline__ float bfhi(uint32_t u) { return __builtin_bit_cast(float, u & 0xffff0000u); }
__device__ __forceinline__ float sig_(float x)  { return 1.0f / (1.0f + __expf(-x)); }
__device__ __forceinline__ float tanh_(float x) { return 1.0f - 2.0f / (1.0f + __expf(2.0f * x)); }

// Issue 16 A-fragment loads, NO wait (progressive vmcnt waits follow).
// sc0 sc1 = read at the LLC (cross-XCD coherence point).
__device__ __forceinline__ void load_a16_issue(const void* p, i32x4* a) {
    asm volatile(
        "global_load_dwordx4 %0, %16, off sc0 sc1\n\t"
        "global_load_dwordx4 %1, %16, off offset:64 sc0 sc1\n\t"
        "global_load_dwordx4 %2, %16, off offset:128 sc0 sc1\n\t"
        "global_load_dwordx4 %3, %16, off offset:192 sc0 sc1\n\t"
        "global_load_dwordx4 %4, %16, off offset:256 sc0 sc1\n\t"
        "global_load_dwordx4 %5, %16, off offset:320 sc0 sc1\n\t"
        "global_load_dwordx4 %6, %16, off offset:384 sc0 sc1\n\t"
        "global_load_dwordx4 %7, %16, off offset:448 sc0 sc1\n\t"
        "global_load_dwordx4 %8, %16, off offset:512 sc0 sc1\n\t"
        "global_load_dwordx4 %9, %16, off offset:576 sc0 sc1\n\t"
        "global_load_dwordx4 %10, %16, off offset:640 sc0 sc1\n\t"
        "global_load_dwordx4 %11, %16, off offset:704 sc0 sc1\n\t"
        "global_load_dwordx4 %12, %16, off offset:768 sc0 sc1\n\t"
        "global_load_dwordx4 %13, %16, off offset:832 sc0 sc1\n\t"
        "global_load_dwordx4 %14, %16, off offset:896 sc0 sc1\n\t"
        "global_load_dwordx4 %15, %16, off offset:960 sc0 sc1"
        : "=v"(a[0]), "=v"(a[1]), "=v"(a[2]), "=v"(a[3]),
          "=v"(a[4]), "=v"(a[5]), "=v"(a[6]), "=v"(a[7]),
          "=v"(a[8]), "=v"(a[9]), "=v"(a[10]), "=v"(a[11]),
          "=v"(a[12]), "=v"(a[13]), "=v"(a[14]), "=v"(a[15])
        : "v"(p)
        : "memory");
}
#define AWAIT(imm, x0, x1, x2, x3) \
    asm volatile("s_waitcnt vmcnt(" #imm ")" : "+v"(x0), "+v"(x1), "+v"(x2), "+v"(x3) :: "memory")

// Write-through-to-LLC h stores (visible device-wide once vmcnt drains).
__device__ __forceinline__ void store_h4(void* p, int h0, int h1, int h2, int h3) {
    asm volatile(
        "global_store_short %4, %0, off sc0 sc1\n\t"
        "global_store_short %4, %1, off offset:1024 sc0 sc1\n\t"
        "global_store_short %4, %2, off offset:2048 sc0 sc1\n\t"
        "global_store_short %4, %3, off offset:3072 sc0 sc1"
        :: "v"(h0), "v"(h1), "v"(h2), "v"(h3), "v"(p)
        : "memory");
}

__global__ void __launch_bounds__(256, 1)
lstm_kernel(const float* __restrict__ values, const float* __restrict__ masks,
            const float* __restrict__ Wih_f, const float* __restrict__ Whh_f,
            const float* __restrict__ bih_f, const float* __restrict__ bhh_f,
            const float* __restrict__ Wih_b, const float* __restrict__ Whh_b,
            const float* __restrict__ bih_b, const float* __restrict__ bhh_b,
            const float* __restrict__ W_imp, const float* __restrict__ b_imp,
            unsigned int* ctrs, short* h_buf, float* hfin)
{
    extern __shared__ char smem_raw[];
    short*    imp_lds = (short*)smem_raw;
    uint32_t* xm_lds  = (uint32_t*)(smem_raw + 16384);

    // flags[16 clusters][16 wgs] dwords: one 64B line per cluster, at ws +256 B
    uint32_t* flags = (uint32_t*)ctrs + 64;

    const int tid  = threadIdx.x;
    const int lane = tid & 63;
    const int wave = tid >> 6;
    const int mw = wave >> 1;      // M-wave: batch half (rows mw*16 .. +15)
    const int nw = wave & 1;       // N-wave: hcol half

    // Static cluster decomposition (bounded, deadlock-impossible).
    const int bid = blockIdx.x;
    const int xg  = bid & 7;       // batch group 0..7
    const int s_  = bid >> 3;
    const int d   = s_ & 1;        // direction
    const int w   = s_ >> 1;       // wg-in-cluster 0..15 (owns hcols w*32..w*32+31)
    const int cluster = xg * 2 + d;

    const float* Whh = d ? Whh_b : Whh_f;
    const float* Wih = d ? Wih_b : Wih_f;
    const float* bih = d ? bih_b : bih_f;
    const float* bhh = d ? bhh_b : bhh_f;

    const int col16 = lane & 15;
    const int koff4 = lane >> 4;                 // 0..3
    const int jcol  = w * 32 + nw * 16 + col16;  // owned h-column

    // ---- stage W_imp B-tile into LDS, replicated across all 16 cols ----
    for (int c = tid; c < 1024; c += 256) {
        int ckoff = (c >> 4) & 3, ckb = c >> 6;
        int k0 = ckb * 32 + ckoff * 8;
        short* dst = &imp_lds[c * 8];
        #pragma unroll
        for (int j = 0; j < 8; ++j) dst[j] = f2bf(W_imp[k0 + j]);
    }
    // ---- stage packed (x*(1-m), m) bf16 pairs for this wg's 32 batch rows ----
    for (int i = tid; i < 32 * 512; i += 256) {
        int r = i >> 9, s = i & 511;
        float x = values[(xg * 32 + r) * S_ + s];
        float m = masks[(xg * 32 + r) * S_ + s];
        float a = x * (1.0f - m);
        xm_lds[r * XM_STRIDE + s] =
            (uint32_t)(uint16_t)f2bf(a) | ((uint32_t)(uint16_t)f2bf(m) << 16);
    }

    // ---- B fragments (4 gate tiles) in registers: 256 VGPRs, static over all steps ----
    s16x8 bfr[4][16];
    {
        const float* base = Whh + (size_t)jcol * 512 + koff4 * 8;
        #pragma unroll
        for (int g = 0; g < 4; ++g) {
            const float* src = base + (size_t)g * 512 * 512;
            #pragma unroll
            for (int kb = 0; kb < 16; ++kb) {
                f32x4 v0 = *(const f32x4*)(src + kb * 32);
                f32x4 v1 = *(const f32x4*)(src + kb * 32 + 4);
                s16x8 b;
                b[0] = f2bf(v0[0]); b[1] = f2bf(v0[1]); b[2] = f2bf(v0[2]); b[3] = f2bf(v0[3]);
                b[4] = f2bf(v1[0]); b[5] = f2bf(v1[1]); b[6] = f2bf(v1[2]); b[7] = f2bf(v1[3]);
                bfr[g][kb] = b;
            }
        }
    }

    float bias[4], wih[4];
    #pragma unroll
    for (int g = 0; g < 4; ++g) {
        int gc = g * 512 + jcol;
        bias[g] = bih[gc] + bhh[gc];
        wih[g]  = Wih[gc];
    }
    const float bimp  = b_imp[0];
    const float start = d ? -128.0f : 128.0f;

    const int arow    = xg * 32 + mw * 16 + col16;      // A-fragment row (abs batch)
    const int rowloc  = mw * 16 + koff4 * 4;            // first local C-row of this lane
    const int rowbase = xg * 32 + rowloc;               // abs
    const int imp_off = (koff4 * 16 + col16) * 8;       // lds chunk offset within a kb block

    uint32_t*       myflag = flags + cluster * 16 + w;
    const uint32_t* pollp  = flags + cluster * 16 + col16;  // 16 flags, 1 LLC line

    __syncthreads();   // LDS staging complete

    // ---- init cell: h0,c0 = lstm_cell(start, 0, 0); post wg flag=1 ----
    float c_reg[4];
    {
        float pre[4];
        #pragma unroll
        for (int g = 0; g < 4; ++g) pre[g] = start * wih[g] + bias[g];
        float i0 = sig_(pre[0]), g0 = tanh_(pre[2]), o0 = sig_(pre[3]);
        float c0 = i0 * g0;
        float h0 = o0 * tanh_(c0);
        #pragma unroll
        for (int r = 0; r < 4; ++r) c_reg[r] = c0;
        int hb16 = (int)(unsigned short)(unsigned)f2bf(h0);
        short* dst = h_buf + d * (B_ * H_) + (size_t)rowbase * H_ + jcol;  // buffer 0 holds h_0
        store_h4(dst, hb16, hb16, hb16, hb16);
    }
    asm volatile("s_waitcnt vmcnt(0)" ::: "memory");
    __syncthreads();   // all 4 waves' init stores drained
    if (tid == 0)
        asm volatile("global_store_dword %0, %1, off sc0 sc1" :: "v"(myflag), "v"(1u) : "memory");

    // ---- sequential scan ----
    for (int t = 0; t < S_; ++t) {
        const int p = t & 1;
        const short* hb_r = h_buf + p       * (2 * B_ * H_) + d * (B_ * H_);
        short*       hb_w = h_buf + (p ^ 1) * (2 * B_ * H_) + d * (B_ * H_);

        // poll: ONLY wave 0 (throttled); waves 1-3 wait at the barrier.
        if (wave == 0) {
            const uint32_t tgt = (uint32_t)(t + 1);
            for (;;) {
                uint32_t f;
                asm volatile("global_load_dword %0, %1, off sc0 sc1\n\ts_waitcnt vmcnt(0)"
                             : "=v"(f) : "v"(pollp) : "memory");
                if (__ballot(f >= tgt) == ~0ull) break;
                __builtin_amdgcn_s_sleep(2);
            }
        }
        __syncthreads();   // release: h(t) fully visible at LLC

        // A fragments from LLC; waits pipelined under MFMA
        i32x4 a_regs[16];
        load_a16_issue(hb_r + (size_t)arow * H_ + koff4 * 8, a_regs);

        f32x4 acc0 = {0,0,0,0}, acc1 = {0,0,0,0}, acc2 = {0,0,0,0}, acc3 = {0,0,0,0};
        f32x4 acc4 = {0,0,0,0};   // imp (W_imp replicated => valid in every lane)
        AWAIT(12, a_regs[0], a_regs[1], a_regs[2], a_regs[3]);
        #pragma unroll
        for (int kb = 0; kb < 4; ++kb) {
            s16x8 a = __builtin_bit_cast(s16x8, a_regs[kb]);
            acc0 = __builtin_amdgcn_mfma_f32_16x16x32_bf16(a, bfr[0][kb], acc0, 0, 0, 0);
            acc1 = __builtin_amdgcn_mfma_f32_16x16x32_bf16(a, bfr[1][kb], acc1, 0, 0, 0);
            acc2 = __builtin_amdgcn_mfma_f32_16x16x32_bf16(a, bfr[2][kb], acc2, 0, 0, 0);
            acc3 = __builtin_amdgcn_mfma_f32_16x16x32_bf16(a, bfr[3][kb], acc3, 0, 0, 0);
            s16x8 b4 = *(const s16x8*)&imp_lds[kb * 512 + imp_off];
            acc4 = __builtin_amdgcn_mfma_f32_16x16x32_bf16(a, b4, acc4, 0, 0, 0);
        }
        AWAIT(8, a_regs[4], a_regs[5], a_regs[6], a_regs[7]);
        #pragma unroll
        for (int kb = 4; kb < 8; ++kb) {
            s16x8 a = __builtin_bit_cast(s16x8, a_regs[kb]);
            acc0 = __builtin_amdgcn_mfma_f32_16x16x32_bf16(a, bfr[0][kb], acc0, 0, 0, 0);
            acc1 = __builtin_amdgcn_mfma_f32_16x16x32_bf16(a, bfr[1][kb], acc1, 0, 0, 0);
            acc2 = __builtin_amdgcn_mfma_f32_16x16x32_bf16(a, bfr[2][kb], acc2, 0, 0, 0);
            acc3 = __builtin_amdgcn_mfma_f32_16x16x32_bf16(a, bfr[3][kb], acc3, 0, 0, 0);
            s16x8 b4 = *(const s16x8*)&imp_lds[kb * 512 + imp_off];
            acc4 = __builtin_amdgcn_mfma_f32_16x16x32_bf16(a, b4, acc4, 0, 0, 0);
        }
        AWAIT(4, a_regs[8], a_regs[9], a_regs[10], a_regs[11]);
        #pragma unroll
        for (int kb = 8; kb < 12; ++kb) {
            s16x8 a = __builtin_bit_cast(s16x8, a_regs[kb]);
            acc0 = __builtin_amdgcn_mfma_f32_16x16x32_bf16(a, bfr[0][kb], acc0, 0, 0, 0);
            acc1 = __builtin_amdgcn_mfma_f32_16x16x32_bf16(a, bfr[1][kb], acc1, 0, 0, 0);
            acc2 = __builtin_amdgcn_mfma_f32_16x16x32_bf16(a, bfr[2][kb], acc2, 0, 0, 0);
            acc3 = __builtin_amdgcn_mfma_f32_16x16x32_bf16(a, bfr[3][kb], acc3, 0, 0, 0);
            s16x8 b4 = *(const s16x8*)&imp_lds[kb * 512 + imp_off];
            acc4 = __builtin_amdgcn_mfma_f32_16x16x32_bf16(a, b4, acc4, 0, 0, 0);
        }
        AWAIT(0, a_regs[12], a_regs[13], a_regs[14], a_regs[15]);
        #pragma unroll
        for (int kb = 12; kb < 16; ++kb) {
            s16x8 a = __builtin_bit_cast(s16x8, a_regs[kb]);
            acc0 = __builtin_amdgcn_mfma_f32_16x16x32_bf16(a, bfr[0][kb], acc0, 0, 0, 0);
            acc1 = __builtin_amdgcn_mfma_f32_16x16x32_bf16(a, bfr[1][kb], acc1, 0, 0, 0);
            acc2 = __builtin_amdgcn_mfma_f32_16x16x32_bf16(a, bfr[2][kb], acc2, 0, 0, 0);
            acc3 = __builtin_amdgcn_mfma_f32_16x16x32_bf16(a, bfr[3][kb], acc3, 0, 0, 0);
            s16x8 b4 = *(const s16x8*)&imp_lds[kb * 512 + imp_off];
            acc4 = __builtin_amdgcn_mfma_f32_16x16x32_bf16(a, b4, acc4, 0, 0, 0);
        }

        // per-lane cc + gates -> c,h (no cross-lane traffic)
        int hbits[4];
        #pragma unroll
        for (int r = 0; r < 4; ++r) {
            uint32_t pk = xm_lds[(rowloc + r) * XM_STRIDE + t];
            float cc = bflo(pk) + bfhi(pk) * (acc4[r] + bimp);
            float pi = acc0[r] + cc * wih[0] + bias[0];
            float pf = acc1[r] + cc * wih[1] + bias[1];
            float pg = acc2[r] + cc * wih[2] + bias[2];
            float po = acc3[r] + cc * wih[3] + bias[3];
            float iv = sig_(pi), fv = sig_(pf), gv = tanh_(pg), ov = sig_(po);
            c_reg[r] = fv * c_reg[r] + iv * gv;
            float hn = ov * tanh_(c_reg[r]);
            hbits[r] = (int)(unsigned short)(unsigned)f2bf(hn);
            if (t == S_ - 1) hfin[d * (B_ * H_) + (rowbase + r) * H_ + jcol] = hn;
        }
        store_h4(hb_w + (size_t)rowbase * H_ + jcol, hbits[0], hbits[1], hbits[2], hbits[3]);

        // drain own stores, wg barrier (all waves drained), then ONE flag store per wg
        asm volatile("s_waitcnt vmcnt(0)" ::: "memory");
        __syncthreads();
        if (tid == 0)
            asm volatile("global_store_dword %0, %1, off sc0 sc1"
                         :: "v"(myflag), "v"((uint32_t)(t + 2)) : "memory");
    }
}

__global__ void __launch_bounds__(256)
epilogue_kernel(const float* __restrict__ values, const float* __restrict__ masks,
                const float* __restrict__ hfin, float* __restrict__ out)
{
    int i = blockIdx.x * 256 + threadIdx.x;          // 0..131071
    float h = hfin[i] + hfin[B_ * H_ + i];           // h_f + h_b
    out[i] = h;                                      // output 0: h (B,H)
    float xv = values[i], mv = masks[i];
    out[B_ * H_ + i] = h * (1.0f - mv) + xv * mv;    // output 1: out (B,S,1)
}

extern "C" void kernel_launch(void* const* d_in, const int* in_sizes, int n_in,
                              void* d_out, int out_size, void* d_ws, size_t ws_size,
                              hipStream_t stream) {
    const float* values = (const float*)d_in[0];
    const float* masks  = (const float*)d_in[1];
    const float* Wih_f  = (const float*)d_in[2];
    const float* Whh_f  = (const float*)d_in[3];
    const float* bih_f  = (const float*)d_in[4];
    const float* bhh_f  = (const float*)d_in[5];
    const float* Wih_b  = (const float*)d_in[6];
    const float* Whh_b  = (const float*)d_in[7];
    const float* bih_b  = (const float*)d_in[8];
    const float* bhh_b  = (const float*)d_in[9];
    const float* W_imp  = (const float*)d_in[10];
    const float* b_imp  = (const float*)d_in[11];

    unsigned int* ctrs = (unsigned int*)d_ws;        // flags[16][16] @ +256 B
    short* h_buf = (short*)((char*)d_ws + 8192);     // 2 bufs x 2 dirs x 256x512 bf16 = 1 MB
    float* hfin  = (float*)((char*)d_ws + 8192 + 2 * 2 * B_ * H_ * sizeof(short));

    hipMemsetAsync(d_ws, 0, 8192, stream);           // zero flags

    hipFuncSetAttribute((const void*)lstm_kernel,
                        hipFuncAttributeMaxDynamicSharedMemorySize, LDS_BYTES);

    void* args[] = {
        (void*)&values, (void*)&masks,
        (void*)&Wih_f, (void*)&Whh_f, (void*)&bih_f, (void*)&bhh_f,
        (void*)&Wih_b, (void*)&Whh_b, (void*)&bih_b, (void*)&bhh_b,
        (void*)&W_imp, (void*)&b_imp,
        (void*)&ctrs, (void*)&h_buf, (void*)&hfin
    };
    hipError_t err = hipLaunchCooperativeKernel((const void*)lstm_kernel,
                                                dim3(256), dim3(256), args,
                                                (unsigned int)LDS_BYTES, stream);
    if (err != hipSuccess) {
        lstm_kernel<<<dim3(256), dim3(256), LDS_BYTES, stream>>>(
            values, masks, Wih_f, Whh_f, bih_f, bhh_f,
            Wih_b, Whh_b, bih_b, bhh_b, W_imp, b_imp, ctrs, h_buf, hfin);
    }

    epilogue_kernel<<<dim3((B_ * H_) / 256), dim3(256), 0, stream>>>(
        values, masks, hfin, (float*)d_out);
}

// Round 7
// 2309.458 us; speedup vs baseline: 1.8439x; 1.1848x over previous
//
#include <hip/hip_runtime.h>
#include <stdint.h>

#define B_ 256
#define S_ 512
#define H_ 512

// Per-wg LDS (bytes):
//   [0,16384)        imp_lds : W_imp B-tile, replicated across all 16 cols
//   [16384,49216)    xm_lds  : packed (x*(1-m), m) bf16 pairs, [16 rows][513 dwords]
// Request 56,320 => floor(163840/56320)=2 wgs/CU: two independent chains per CU.
#define XM_STRIDE 513
#define LDS_BYTES 56320

typedef __attribute__((ext_vector_type(4))) float f32x4;
typedef __attribute__((ext_vector_type(4))) int   i32x4;
typedef __attribute__((ext_vector_type(8))) short s16x8;

__device__ __forceinline__ short f2bf(float f) {
    union { float f; uint32_t u; } c; c.f = f;
    uint32_t u = c.u;
    u += 0x7fffu + ((u >> 16) & 1u);   // round-to-nearest-even
    return (short)(u >> 16);
}
__device__ __forceinline__ float bflo(uint32_t u) { return __builtin_bit_cast(float, u << 16); }
__device__ __forceinline__ float bfhi(uint32_t u) { return __builtin_bit_cast(float, u & 0xffff0000u); }
__device__ __forceinline__ float sig_(float x)  { return 1.0f / (1.0f + __expf(-x)); }
__device__ __forceinline__ float tanh_(float x) { return 1.0f - 2.0f / (1.0f + __expf(2.0f * x)); }

// Issue 16 A-fragment loads, NO wait (progressive vmcnt waits follow).
// sc0 sc1 = read at the LLC (cross-XCD coherence point).
__device__ __forceinline__ void load_a16_issue(const void* p, i32x4* a) {
    asm volatile(
        "global_load_dwordx4 %0, %16, off sc0 sc1\n\t"
        "global_load_dwordx4 %1, %16, off offset:64 sc0 sc1\n\t"
        "global_load_dwordx4 %2, %16, off offset:128 sc0 sc1\n\t"
        "global_load_dwordx4 %3, %16, off offset:192 sc0 sc1\n\t"
        "global_load_dwordx4 %4, %16, off offset:256 sc0 sc1\n\t"
        "global_load_dwordx4 %5, %16, off offset:320 sc0 sc1\n\t"
        "global_load_dwordx4 %6, %16, off offset:384 sc0 sc1\n\t"
        "global_load_dwordx4 %7, %16, off offset:448 sc0 sc1\n\t"
        "global_load_dwordx4 %8, %16, off offset:512 sc0 sc1\n\t"
        "global_load_dwordx4 %9, %16, off offset:576 sc0 sc1\n\t"
        "global_load_dwordx4 %10, %16, off offset:640 sc0 sc1\n\t"
        "global_load_dwordx4 %11, %16, off offset:704 sc0 sc1\n\t"
        "global_load_dwordx4 %12, %16, off offset:768 sc0 sc1\n\t"
        "global_load_dwordx4 %13, %16, off offset:832 sc0 sc1\n\t"
        "global_load_dwordx4 %14, %16, off offset:896 sc0 sc1\n\t"
        "global_load_dwordx4 %15, %16, off offset:960 sc0 sc1"
        : "=v"(a[0]), "=v"(a[1]), "=v"(a[2]), "=v"(a[3]),
          "=v"(a[4]), "=v"(a[5]), "=v"(a[6]), "=v"(a[7]),
          "=v"(a[8]), "=v"(a[9]), "=v"(a[10]), "=v"(a[11]),
          "=v"(a[12]), "=v"(a[13]), "=v"(a[14]), "=v"(a[15])
        : "v"(p)
        : "memory");
}
#define AWAIT(imm, x0, x1, x2, x3) \
    asm volatile("s_waitcnt vmcnt(" #imm ")" : "+v"(x0), "+v"(x1), "+v"(x2), "+v"(x3) :: "memory")

// Write-through-to-LLC h stores (visible device-wide once vmcnt drains).
__device__ __forceinline__ void store_h4(void* p, int h0, int h1, int h2, int h3) {
    asm volatile(
        "global_store_short %4, %0, off sc0 sc1\n\t"
        "global_store_short %4, %1, off offset:1024 sc0 sc1\n\t"
        "global_store_short %4, %2, off offset:2048 sc0 sc1\n\t"
        "global_store_short %4, %3, off offset:3072 sc0 sc1"
        :: "v"(h0), "v"(h1), "v"(h2), "v"(h3), "v"(p)
        : "memory");
}

__global__ void __launch_bounds__(128, 1)
lstm_kernel(const float* __restrict__ values, const float* __restrict__ masks,
            const float* __restrict__ Wih_f, const float* __restrict__ Whh_f,
            const float* __restrict__ bih_f, const float* __restrict__ bhh_f,
            const float* __restrict__ Wih_b, const float* __restrict__ Whh_b,
            const float* __restrict__ bih_b, const float* __restrict__ bhh_b,
            const float* __restrict__ W_imp, const float* __restrict__ b_imp,
            unsigned int* ctrs, short* h_buf, float* hfin)
{
    extern __shared__ char smem_raw[];
    short*    imp_lds = (short*)smem_raw;
    uint32_t* xm_lds  = (uint32_t*)(smem_raw + 16384);

    // flags[32 clusters][16 wgs] dwords: one 64B line per cluster, at ws +256 B
    uint32_t* flags = (uint32_t*)ctrs + 64;

    const int tid  = threadIdx.x;
    const int lane = tid & 63;
    const int wave = tid >> 6;     // 0..1 ; doubles as N-half (nw)
    const int nw = wave;

    // Decomposition: 16 batch-groups of 16 rows x 2 dirs x 16 col-wgs = 512 wgs.
    // d = bid>>8 so wg i and i+256 (likely co-resident on one CU) differ in
    // direction => different clusters => decorrelated stall phases.
    const int bid = blockIdx.x;
    const int g   = bid & 15;          // batch group (rows g*16..+15)
    const int w   = (bid >> 4) & 15;   // col-wg (owns hcols w*32..w*32+31)
    const int d   = bid >> 8;          // direction
    const int cluster = d * 16 + g;

    const float* Whh = d ? Whh_b : Whh_f;
    const float* Wih = d ? Wih_b : Wih_f;
    const float* bih = d ? bih_b : bih_f;
    const float* bhh = d ? bhh_b : bhh_f;

    const int col16 = lane & 15;
    const int koff4 = lane >> 4;                 // 0..3
    const int jcol  = w * 32 + nw * 16 + col16;  // owned h-column

    // ---- stage W_imp B-tile into LDS, replicated across all 16 cols ----
    for (int c = tid; c < 1024; c += 128) {
        int ckoff = (c >> 4) & 3, ckb = c >> 6;
        int k0 = ckb * 32 + ckoff * 8;
        short* dst = &imp_lds[c * 8];
        #pragma unroll
        for (int j = 0; j < 8; ++j) dst[j] = f2bf(W_imp[k0 + j]);
    }
    // ---- stage packed (x*(1-m), m) bf16 pairs for this wg's 16 batch rows ----
    for (int i = tid; i < 16 * 512; i += 128) {
        int r = i >> 9, s = i & 511;
        float x = values[(g * 16 + r) * S_ + s];
        float m = masks[(g * 16 + r) * S_ + s];
        float a = x * (1.0f - m);
        xm_lds[r * XM_STRIDE + s] =
            (uint32_t)(uint16_t)f2bf(a) | ((uint32_t)(uint16_t)f2bf(m) << 16);
    }

    // ---- B fragments (4 gate tiles) in registers: 256 VGPRs, static over all steps ----
    s16x8 bfr[4][16];
    {
        const float* base = Whh + (size_t)jcol * 512 + koff4 * 8;
        #pragma unroll
        for (int gg = 0; gg < 4; ++gg) {
            const float* src = base + (size_t)gg * 512 * 512;
            #pragma unroll
            for (int kb = 0; kb < 16; ++kb) {
                f32x4 v0 = *(const f32x4*)(src + kb * 32);
                f32x4 v1 = *(const f32x4*)(src + kb * 32 + 4);
                s16x8 b;
                b[0] = f2bf(v0[0]); b[1] = f2bf(v0[1]); b[2] = f2bf(v0[2]); b[3] = f2bf(v0[3]);
                b[4] = f2bf(v1[0]); b[5] = f2bf(v1[1]); b[6] = f2bf(v1[2]); b[7] = f2bf(v1[3]);
                bfr[gg][kb] = b;
            }
        }
    }

    float bias[4], wih[4];
    #pragma unroll
    for (int gg = 0; gg < 4; ++gg) {
        int gc = gg * 512 + jcol;
        bias[gg] = bih[gc] + bhh[gc];
        wih[gg]  = Wih[gc];
    }
    const float bimp  = b_imp[0];
    const float start = d ? -128.0f : 128.0f;

    const int arow    = g * 16 + col16;           // A-fragment row (abs batch)
    const int rowloc  = koff4 * 4;                // first local C-row of this lane
    const int rowbase = g * 16 + rowloc;          // abs
    const int imp_off = (koff4 * 16 + col16) * 8; // lds chunk offset within a kb block

    uint32_t*       myflag = flags + cluster * 16 + w;
    const uint32_t* pollp  = flags + cluster * 16 + col16;  // 16 flags, 1 LLC line

    __syncthreads();   // LDS staging complete (2 waves)

    // ---- init cell: h0,c0 = lstm_cell(start, 0, 0); post wg flag=1 ----
    float c_reg[4];
    {
        float pre[4];
        #pragma unroll
        for (int gg = 0; gg < 4; ++gg) pre[gg] = start * wih[gg] + bias[gg];
        float i0 = sig_(pre[0]), g0 = tanh_(pre[2]), o0 = sig_(pre[3]);
        float c0 = i0 * g0;
        float h0 = o0 * tanh_(c0);
        #pragma unroll
        for (int r = 0; r < 4; ++r) c_reg[r] = c0;
        int hb16 = (int)(unsigned short)(unsigned)f2bf(h0);
        short* dst = h_buf + d * (B_ * H_) + (size_t)rowbase * H_ + jcol;  // buffer 0 = h_0
        store_h4(dst, hb16, hb16, hb16, hb16);
    }
    asm volatile("s_waitcnt vmcnt(0)" ::: "memory");
    __syncthreads();   // both waves' init stores drained
    if (tid == 0)
        asm volatile("global_store_dword %0, %1, off sc0 sc1" :: "v"(myflag), "v"(1u) : "memory");

    // ---- sequential scan ----
    for (int t = 0; t < S_; ++t) {
        const int p = t & 1;
        const short* hb_r = h_buf + p       * (2 * B_ * H_) + d * (B_ * H_);
        short*       hb_w = h_buf + (p ^ 1) * (2 * B_ * H_) + d * (B_ * H_);

        // poll: ONLY wave 0 (throttled); wave 1 waits at the barrier.
        if (wave == 0) {
            const uint32_t tgt = (uint32_t)(t + 1);
            for (;;) {
                uint32_t f;
                asm volatile("global_load_dword %0, %1, off sc0 sc1\n\ts_waitcnt vmcnt(0)"
                             : "=v"(f) : "v"(pollp) : "memory");
                if (__ballot(f >= tgt) == ~0ull) break;
                __builtin_amdgcn_s_sleep(2);
            }
        }
        __syncthreads();   // release: h(t) fully visible at LLC

        // A fragments from LLC; waits pipelined under MFMA
        i32x4 a_regs[16];
        load_a16_issue(hb_r + (size_t)arow * H_ + koff4 * 8, a_regs);

        f32x4 acc0 = {0,0,0,0}, acc1 = {0,0,0,0}, acc2 = {0,0,0,0}, acc3 = {0,0,0,0};
        f32x4 acc4 = {0,0,0,0};   // imp (W_imp replicated => valid in every lane)
        AWAIT(12, a_regs[0], a_regs[1], a_regs[2], a_regs[3]);
        #pragma unroll
        for (int kb = 0; kb < 4; ++kb) {
            s16x8 a = __builtin_bit_cast(s16x8, a_regs[kb]);
            acc0 = __builtin_amdgcn_mfma_f32_16x16x32_bf16(a, bfr[0][kb], acc0, 0, 0, 0);
            acc1 = __builtin_amdgcn_mfma_f32_16x16x32_bf16(a, bfr[1][kb], acc1, 0, 0, 0);
            acc2 = __builtin_amdgcn_mfma_f32_16x16x32_bf16(a, bfr[2][kb], acc2, 0, 0, 0);
            acc3 = __builtin_amdgcn_mfma_f32_16x16x32_bf16(a, bfr[3][kb], acc3, 0, 0, 0);
            s16x8 b4 = *(const s16x8*)&imp_lds[kb * 512 + imp_off];
            acc4 = __builtin_amdgcn_mfma_f32_16x16x32_bf16(a, b4, acc4, 0, 0, 0);
        }
        AWAIT(8, a_regs[4], a_regs[5], a_regs[6], a_regs[7]);
        #pragma unroll
        for (int kb = 4; kb < 8; ++kb) {
            s16x8 a = __builtin_bit_cast(s16x8, a_regs[kb]);
            acc0 = __builtin_amdgcn_mfma_f32_16x16x32_bf16(a, bfr[0][kb], acc0, 0, 0, 0);
            acc1 = __builtin_amdgcn_mfma_f32_16x16x32_bf16(a, bfr[1][kb], acc1, 0, 0, 0);
            acc2 = __builtin_amdgcn_mfma_f32_16x16x32_bf16(a, bfr[2][kb], acc2, 0, 0, 0);
            acc3 = __builtin_amdgcn_mfma_f32_16x16x32_bf16(a, bfr[3][kb], acc3, 0, 0, 0);
            s16x8 b4 = *(const s16x8*)&imp_lds[kb * 512 + imp_off];
            acc4 = __builtin_amdgcn_mfma_f32_16x16x32_bf16(a, b4, acc4, 0, 0, 0);
        }
        AWAIT(4, a_regs[8], a_regs[9], a_regs[10], a_regs[11]);
        #pragma unroll
        for (int kb = 8; kb < 12; ++kb) {
            s16x8 a = __builtin_bit_cast(s16x8, a_regs[kb]);
            acc0 = __builtin_amdgcn_mfma_f32_16x16x32_bf16(a, bfr[0][kb], acc0, 0, 0, 0);
            acc1 = __builtin_amdgcn_mfma_f32_16x16x32_bf16(a, bfr[1][kb], acc1, 0, 0, 0);
            acc2 = __builtin_amdgcn_mfma_f32_16x16x32_bf16(a, bfr[2][kb], acc2, 0, 0, 0);
            acc3 = __builtin_amdgcn_mfma_f32_16x16x32_bf16(a, bfr[3][kb], acc3, 0, 0, 0);
            s16x8 b4 = *(const s16x8*)&imp_lds[kb * 512 + imp_off];
            acc4 = __builtin_amdgcn_mfma_f32_16x16x32_bf16(a, b4, acc4, 0, 0, 0);
        }
        AWAIT(0, a_regs[12], a_regs[13], a_regs[14], a_regs[15]);
        #pragma unroll
        for (int kb = 12; kb < 16; ++kb) {
            s16x8 a = __builtin_bit_cast(s16x8, a_regs[kb]);
            acc0 = __builtin_amdgcn_mfma_f32_16x16x32_bf16(a, bfr[0][kb], acc0, 0, 0, 0);
            acc1 = __builtin_amdgcn_mfma_f32_16x16x32_bf16(a, bfr[1][kb], acc1, 0, 0, 0);
            acc2 = __builtin_amdgcn_mfma_f32_16x16x32_bf16(a, bfr[2][kb], acc2, 0, 0, 0);
            acc3 = __builtin_amdgcn_mfma_f32_16x16x32_bf16(a, bfr[3][kb], acc3, 0, 0, 0);
            s16x8 b4 = *(const s16x8*)&imp_lds[kb * 512 + imp_off];
            acc4 = __builtin_amdgcn_mfma_f32_16x16x32_bf16(a, b4, acc4, 0, 0, 0);
        }

        // per-lane cc + gates -> c,h (no cross-lane traffic)
        int hbits[4];
        #pragma unroll
        for (int r = 0; r < 4; ++r) {
            uint32_t pk = xm_lds[(rowloc + r) * XM_STRIDE + t];
            float cc = bflo(pk) + bfhi(pk) * (acc4[r] + bimp);
            float pi = acc0[r] + cc * wih[0] + bias[0];
            float pf = acc1[r] + cc * wih[1] + bias[1];
            float pg = acc2[r] + cc * wih[2] + bias[2];
            float po = acc3[r] + cc * wih[3] + bias[3];
            float iv = sig_(pi), fv = sig_(pf), gv = tanh_(pg), ov = sig_(po);
            c_reg[r] = fv * c_reg[r] + iv * gv;
            float hn = ov * tanh_(c_reg[r]);
            hbits[r] = (int)(unsigned short)(unsigned)f2bf(hn);
            if (t == S_ - 1) hfin[d * (B_ * H_) + (rowbase + r) * H_ + jcol] = hn;
        }
        store_h4(hb_w + (size_t)rowbase * H_ + jcol, hbits[0], hbits[1], hbits[2], hbits[3]);

        // drain own stores, wg barrier (both waves drained), then ONE flag store per wg
        asm volatile("s_waitcnt vmcnt(0)" ::: "memory");
        __syncthreads();
        if (tid == 0)
            asm volatile("global_store_dword %0, %1, off sc0 sc1"
                         :: "v"(myflag), "v"((uint32_t)(t + 2)) : "memory");
    }
}

__global__ void __launch_bounds__(256)
epilogue_kernel(const float* __restrict__ values, const float* __restrict__ masks,
                const float* __restrict__ hfin, float* __restrict__ out)
{
    int i = blockIdx.x * 256 + threadIdx.x;          // 0..131071
    float h = hfin[i] + hfin[B_ * H_ + i];           // h_f + h_b
    out[i] = h;                                      // output 0: h (B,H)
    float xv = values[i], mv = masks[i];
    out[B_ * H_ + i] = h * (1.0f - mv) + xv * mv;    // output 1: out (B,S,1)
}

extern "C" void kernel_launch(void* const* d_in, const int* in_sizes, int n_in,
                              void* d_out, int out_size, void* d_ws, size_t ws_size,
                              hipStream_t stream) {
    const float* values = (const float*)d_in[0];
    const float* masks  = (const float*)d_in[1];
    const float* Wih_f  = (const float*)d_in[2];
    const float* Whh_f  = (const float*)d_in[3];
    const float* bih_f  = (const float*)d_in[4];
    const float* bhh_f  = (const float*)d_in[5];
    const float* Wih_b  = (const float*)d_in[6];
    const float* Whh_b  = (const float*)d_in[7];
    const float* bih_b  = (const float*)d_in[8];
    const float* bhh_b  = (const float*)d_in[9];
    const float* W_imp  = (const float*)d_in[10];
    const float* b_imp  = (const float*)d_in[11];

    unsigned int* ctrs = (unsigned int*)d_ws;        // flags[32][16] @ +256 B
    short* h_buf = (short*)((char*)d_ws + 8192);     // 2 bufs x 2 dirs x 256x512 bf16 = 1 MB
    float* hfin  = (float*)((char*)d_ws + 8192 + 2 * 2 * B_ * H_ * sizeof(short));

    hipMemsetAsync(d_ws, 0, 8192, stream);           // zero flags

    hipFuncSetAttribute((const void*)lstm_kernel,
                        hipFuncAttributeMaxDynamicSharedMemorySize, LDS_BYTES);

    void* args[] = {
        (void*)&values, (void*)&masks,
        (void*)&Wih_f, (void*)&Whh_f, (void*)&bih_f, (void*)&bhh_f,
        (void*)&Wih_b, (void*)&Whh_b, (void*)&bih_b, (void*)&bhh_b,
        (void*)&W_imp, (void*)&b_imp,
        (void*)&ctrs, (void*)&h_buf, (void*)&hfin
    };
    hipError_t err = hipLaunchCooperativeKernel((const void*)lstm_kernel,
                                                dim3(512), dim3(128), args,
                                                (unsigned int)LDS_BYTES, stream);
    if (err != hipSuccess) {
        lstm_kernel<<<dim3(512), dim3(128), LDS_BYTES, stream>>>(
            values, masks, Wih_f, Whh_f, bih_f, bhh_f,
            Wih_b, Whh_b, bih_b, bhh_b, W_imp, b_imp, ctrs, h_buf, hfin);
    }

    epilogue_kernel<<<dim3((B_ * H_) / 256), dim3(256), 0, stream>>>(
        values, masks, hfin, (float*)d_out);
}